// Round 1
// baseline (926.578 us; speedup 1.0000x reference)
//
#include <hip/hip_runtime.h>

#define NCH 32
#define INCH 128

// ---- degree -----------------------------------------------------------------
__global__ void k_init_deg(float* deg, int N) {
  int i = blockIdx.x * blockDim.x + threadIdx.x;
  if (i < N) deg[i] = 1.0f;  // self-loop contributes 1 to every node
}

__global__ void k_count_deg(const int* __restrict__ ei, float* deg, int E) {
  int e = blockIdx.x * blockDim.x + threadIdx.x;
  if (e < E) atomicAdd(&deg[ei[E + e]], 1.0f);  // dst row of edge_index
}

__global__ void k_rsqrt(float* deg, int N) {
  int i = blockIdx.x * blockDim.x + threadIdx.x;
  if (i < N) deg[i] = rsqrtf(deg[i]);  // deg >= 1 always (self-loops)
}

// ---- layer 1 linear: hs[n][c] = (x[n]·W1[:,c]) * dis[n]; agg init = hs ------
__global__ void k_gemm1(const float* __restrict__ x, const float* __restrict__ W1,
                        const float* __restrict__ dis,
                        float* __restrict__ hs, float* __restrict__ agg, int N) {
  __shared__ float w[INCH * NCH];
  for (int i = threadIdx.x; i < INCH * NCH; i += blockDim.x) w[i] = W1[i];
  __syncthreads();
  int t = blockIdx.x * blockDim.x + threadIdx.x;
  int n = t >> 5, c = t & 31;
  if (n >= N) return;
  const float* xr = x + (size_t)n * INCH;
  float acc = 0.f;
#pragma unroll
  for (int k = 0; k < INCH; ++k) acc = fmaf(xr[k], w[k * NCH + c], acc);
  float v = acc * dis[n];
  hs[(size_t)n * NCH + c] = v;
  agg[(size_t)n * NCH + c] = v;  // self-loop init
}

// ---- edge scatter: agg[dst][c] += hs[src][c] --------------------------------
__global__ void k_scatter(const int* __restrict__ ei, const float* __restrict__ hs,
                          float* agg, int E) {
  long long i = (long long)blockIdx.x * blockDim.x + threadIdx.x;
  if (i >= (long long)E * NCH) return;
  int e = (int)(i >> 5), c = (int)(i & 31);
  int s = ei[e];
  int d = ei[E + e];
  atomicAdd(&agg[(size_t)d * NCH + c], hs[(size_t)s * NCH + c]);
}

// ---- layer 2: t = relu(agg*dis + b1); hs2 = (t @ W2) * dis; agg re-init -----
__global__ void k_gemm2(float* aggio, const float* __restrict__ W2,
                        const float* __restrict__ b1, const float* __restrict__ dis,
                        float* __restrict__ hs2, int N) {
  __shared__ float w[NCH * NCH];
  __shared__ float tl[8][NCH];
  int tid = threadIdx.x;
  for (int i = tid; i < NCH * NCH; i += blockDim.x) w[i] = W2[i];
  int t = blockIdx.x * blockDim.x + tid;
  int n = t >> 5, c = t & 31, ln = tid >> 5;
  float d = (n < N) ? dis[n] : 0.f;
  // stage relu(agg*dis + b1) rows into LDS (reads of aggio complete here)
  tl[ln][c] = (n < N) ? fmaxf(fmaf(aggio[(size_t)n * NCH + c], d, b1[c]), 0.f) : 0.f;
  __syncthreads();
  if (n >= N) return;
  float acc = 0.f;
#pragma unroll
  for (int k = 0; k < NCH; ++k) acc = fmaf(tl[ln][k], w[k * NCH + c], acc);
  float v = acc * d;
  hs2[(size_t)n * NCH + c] = v;
  aggio[(size_t)n * NCH + c] = v;  // self-loop init for layer-2 aggregation
}

// ---- head: v = relu(agg*dis + b2); out[n][j] = v · Wc[:,j] + bc[j] ----------
__global__ void k_final(const float* __restrict__ agg, const float* __restrict__ b2,
                        const float* __restrict__ dis, const float* __restrict__ Wc,
                        const float* __restrict__ bc, float* __restrict__ out, int N) {
  int t = blockIdx.x * blockDim.x + threadIdx.x;
  int n = t >> 5, c = t & 31;
  if (n >= N) return;
  float v = fmaxf(fmaf(agg[(size_t)n * NCH + c], dis[n], b2[c]), 0.f);
  float s0 = v * Wc[c * 2 + 0];
  float s1 = v * Wc[c * 2 + 1];
#pragma unroll
  for (int off = 16; off > 0; off >>= 1) {
    s0 += __shfl_down(s0, off, 32);
    s1 += __shfl_down(s1, off, 32);
  }
  if (c == 0) {
    out[(size_t)n * 2 + 0] = s0 + bc[0];
    out[(size_t)n * 2 + 1] = s1 + bc[1];
  }
}

extern "C" void kernel_launch(void* const* d_in, const int* in_sizes, int n_in,
                              void* d_out, int out_size, void* d_ws, size_t ws_size,
                              hipStream_t stream) {
  const float* x  = (const float*)d_in[0];
  const int*   ei = (const int*)d_in[1];
  const float* W1 = (const float*)d_in[2];
  const float* b1 = (const float*)d_in[3];
  const float* W2 = (const float*)d_in[4];
  const float* b2 = (const float*)d_in[5];
  const float* Wc = (const float*)d_in[6];
  const float* bc = (const float*)d_in[7];
  float* out = (float*)d_out;

  const int N = in_sizes[0] / INCH;  // 100000
  const int E = in_sizes[1] / 2;     // 3200000

  float* dis  = (float*)d_ws;              // N floats (deg -> dis in place)
  float* bufA = dis + N;                   // N*32: hs (pre-scaled features)
  float* bufB = bufA + (size_t)N * NCH;    // N*32: aggregation accumulator

  const int bn = 256;
  const int gN   = (N + bn - 1) / bn;
  const int gE   = (E + bn - 1) / bn;
  const int gN32 = (int)(((long long)N * NCH + bn - 1) / bn);
  const int gE32 = (int)(((long long)E * NCH + bn - 1) / bn);

  k_init_deg<<<gN, bn, 0, stream>>>(dis, N);
  k_count_deg<<<gE, bn, 0, stream>>>(ei, dis, E);
  k_rsqrt<<<gN, bn, 0, stream>>>(dis, N);

  // layer 1
  k_gemm1<<<gN32, bn, 0, stream>>>(x, W1, dis, bufA, bufB, N);
  k_scatter<<<gE32, bn, 0, stream>>>(ei, bufA, bufB, E);

  // layer 2 (reads bufB, writes hs2->bufA and re-inits bufB)
  k_gemm2<<<gN32, bn, 0, stream>>>(bufB, W2, b1, dis, bufA, N);
  k_scatter<<<gE32, bn, 0, stream>>>(ei, bufA, bufB, E);

  // classifier head
  k_final<<<gN32, bn, 0, stream>>>(bufB, b2, dis, Wc, bc, out, N);
}

// Round 2
// 718.010 us; speedup vs baseline: 1.2905x; 1.2905x over previous
//
#include <hip/hip_runtime.h>

#define NCH 32
#define INCH 128
#define SCAN_CHUNK 4096  // elements per blockscan block (256 thr x 16)

// ---- CSR build: histogram -> prefix scan -> placement -----------------------
__global__ void k_zero(int* p, int n) {
  int i = blockIdx.x * blockDim.x + threadIdx.x;
  if (i < n) p[i] = 0;
}

__global__ void k_cnt(const int* __restrict__ ei, int* cnt, int E) {
  int e = blockIdx.x * blockDim.x + threadIdx.x;
  if (e < E) atomicAdd(&cnt[ei[E + e]], 1);  // dst row
}

__global__ void k_dis(const int* __restrict__ cnt, float* __restrict__ dis, int N) {
  int i = blockIdx.x * blockDim.x + threadIdx.x;
  if (i < N) dis[i] = rsqrtf((float)(cnt[i] + 1));  // +1 self-loop
}

// exclusive prefix within 4096-elem chunks; per-chunk totals to bsum
__global__ void k_blockscan(const int* __restrict__ cnt, int* __restrict__ pre,
                            int* __restrict__ bsum, int N) {
  __shared__ int wsums[4];
  int base = blockIdx.x * SCAN_CHUNK;
  int tid = threadIdx.x;
  int vals[16];
  int loc = 0;
#pragma unroll
  for (int i = 0; i < 16; ++i) {
    int idx = base + tid * 16 + i;
    int v = (idx < N) ? cnt[idx] : 0;
    vals[i] = loc;  // thread-local exclusive prefix
    loc += v;
  }
  int lane = tid & 63, w = tid >> 6;
  int sc = loc;  // wave-inclusive scan of thread totals
#pragma unroll
  for (int off = 1; off < 64; off <<= 1) {
    int t = __shfl_up(sc, off, 64);
    if (lane >= off) sc += t;
  }
  if (lane == 63) wsums[w] = sc;
  __syncthreads();
  int woff = 0;
  for (int i = 0; i < w; ++i) woff += wsums[i];
  int texcl = woff + (sc - loc);
#pragma unroll
  for (int i = 0; i < 16; ++i) {
    int idx = base + tid * 16 + i;
    if (idx < N) pre[idx] = texcl + vals[i];
  }
  if (tid == 255) bsum[blockIdx.x] = woff + sc;
}

__global__ void k_scanb(int* bsum, int NB) {  // single 64-thread block
  int tid = threadIdx.x;
  int v = (tid < NB) ? bsum[tid] : 0;
  int sc = v;
#pragma unroll
  for (int off = 1; off < 64; off <<= 1) {
    int t = __shfl_up(sc, off, 64);
    if (tid >= off) sc += t;
  }
  if (tid < NB) bsum[tid] = sc - v;  // exclusive
}

__global__ void k_addoff(int* __restrict__ pre, const int* __restrict__ bsum,
                         int* __restrict__ cursor, int N, int E) {
  int i = blockIdx.x * blockDim.x + threadIdx.x;
  if (i < N) {
    int v = pre[i] + bsum[i >> 12];
    pre[i] = v;
    cursor[i] = v;
  }
  if (i == 0) pre[N] = E;
}

__global__ void k_place(const int* __restrict__ ei, int* cursor,
                        int* __restrict__ srcs, int E) {
  int e = blockIdx.x * blockDim.x + threadIdx.x;
  if (e < E) {
    int d = ei[E + e];
    int p = atomicAdd(&cursor[d], 1);
    srcs[p] = ei[e];
  }
}

// ---- layer 1 linear: hs[n][c] = (x[n]·W1[:,c]) * dis[n] ---------------------
__global__ void k_gemm1(const float* __restrict__ x, const float* __restrict__ W1,
                        const float* __restrict__ dis, float* __restrict__ hs, int N) {
  __shared__ float w[INCH * NCH];
  for (int i = threadIdx.x; i < INCH * NCH; i += blockDim.x) w[i] = W1[i];
  __syncthreads();
  int t = blockIdx.x * blockDim.x + threadIdx.x;
  int n = t >> 5, c = t & 31;
  if (n >= N) return;
  const float* xr = x + (size_t)n * INCH;
  float acc = 0.f;
#pragma unroll
  for (int k = 0; k < INCH; ++k) acc = fmaf(xr[k], w[k * NCH + c], acc);
  hs[(size_t)n * NCH + c] = acc * dis[n];
}

// ---- agg layer1: t[n][c] = relu(dis[n]*(hs[n][c]+Σ_src hs[src][c]) + b1[c]) -
__global__ void k_agg1(const int* __restrict__ rowptr, const int* __restrict__ srcs,
                       const float* __restrict__ hs, const float* __restrict__ dis,
                       const float* __restrict__ b1, float* __restrict__ out, int N) {
  int t = blockIdx.x * blockDim.x + threadIdx.x;
  int n = t >> 5, c = t & 31;
  if (n >= N) return;
  int j = rowptr[n], end = rowptr[n + 1];
  float acc = hs[(size_t)n * NCH + c];  // self loop
  for (; j + 4 <= end; j += 4) {
    int s0 = srcs[j], s1 = srcs[j + 1], s2 = srcs[j + 2], s3 = srcs[j + 3];
    float a0 = hs[(size_t)s0 * NCH + c];
    float a1 = hs[(size_t)s1 * NCH + c];
    float a2 = hs[(size_t)s2 * NCH + c];
    float a3 = hs[(size_t)s3 * NCH + c];
    acc += (a0 + a1) + (a2 + a3);
  }
  for (; j < end; ++j) acc += hs[(size_t)srcs[j] * NCH + c];
  out[(size_t)n * NCH + c] = fmaxf(fmaf(acc, dis[n], b1[c]), 0.f);
}

// ---- layer 2 linear via shuffles: hs2 = (t @ W2) * dis ----------------------
__global__ void k_gemm2(const float* __restrict__ t, const float* __restrict__ W2,
                        const float* __restrict__ dis, float* __restrict__ hs2, int N) {
  __shared__ float w[NCH * NCH];
  for (int i = threadIdx.x; i < NCH * NCH; i += blockDim.x) w[i] = W2[i];
  __syncthreads();
  int tt = blockIdx.x * blockDim.x + threadIdx.x;
  int n = tt >> 5, c = tt & 31;
  if (n >= N) return;
  float tv = t[(size_t)n * NCH + c];
  float acc = 0.f;
#pragma unroll
  for (int k = 0; k < NCH; ++k) acc = fmaf(__shfl(tv, k, 32), w[k * NCH + c], acc);
  hs2[(size_t)n * NCH + c] = acc * dis[n];
}

// ---- agg layer2 + head: v=relu(dis*(self+Σ)+b2); out[n] = v·Wc + bc ---------
__global__ void k_agg2_head(const int* __restrict__ rowptr, const int* __restrict__ srcs,
                            const float* __restrict__ hs2, const float* __restrict__ dis,
                            const float* __restrict__ b2, const float* __restrict__ Wc,
                            const float* __restrict__ bc, float* __restrict__ out, int N) {
  int t = blockIdx.x * blockDim.x + threadIdx.x;
  int n = t >> 5, c = t & 31;
  if (n >= N) return;
  int j = rowptr[n], end = rowptr[n + 1];
  float acc = hs2[(size_t)n * NCH + c];
  for (; j + 4 <= end; j += 4) {
    int s0 = srcs[j], s1 = srcs[j + 1], s2 = srcs[j + 2], s3 = srcs[j + 3];
    float a0 = hs2[(size_t)s0 * NCH + c];
    float a1 = hs2[(size_t)s1 * NCH + c];
    float a2 = hs2[(size_t)s2 * NCH + c];
    float a3 = hs2[(size_t)s3 * NCH + c];
    acc += (a0 + a1) + (a2 + a3);
  }
  for (; j < end; ++j) acc += hs2[(size_t)srcs[j] * NCH + c];
  float v = fmaxf(fmaf(acc, dis[n], b2[c]), 0.f);
  float s0 = v * Wc[c * 2 + 0];
  float s1 = v * Wc[c * 2 + 1];
#pragma unroll
  for (int off = 16; off > 0; off >>= 1) {
    s0 += __shfl_down(s0, off, 32);
    s1 += __shfl_down(s1, off, 32);
  }
  if (c == 0) {
    out[(size_t)n * 2 + 0] = s0 + bc[0];
    out[(size_t)n * 2 + 1] = s1 + bc[1];
  }
}

extern "C" void kernel_launch(void* const* d_in, const int* in_sizes, int n_in,
                              void* d_out, int out_size, void* d_ws, size_t ws_size,
                              hipStream_t stream) {
  const float* x  = (const float*)d_in[0];
  const int*   ei = (const int*)d_in[1];
  const float* W1 = (const float*)d_in[2];
  const float* b1 = (const float*)d_in[3];
  const float* W2 = (const float*)d_in[4];
  const float* b2 = (const float*)d_in[5];
  const float* Wc = (const float*)d_in[6];
  const float* bc = (const float*)d_in[7];
  float* out = (float*)d_out;

  const int N = in_sizes[0] / INCH;  // 100000
  const int E = in_sizes[1] / 2;     // 3200000

  // workspace layout (all 4B elems)
  float* dis    = (float*)d_ws;                 // N
  int*   rowptr = (int*)(dis + N);              // N+4 (pad)
  int*   cursor = rowptr + N + 4;               // N
  int*   bsum   = cursor + N;                   // 64
  int*   srcs   = bsum + 64;                    // E
  float* bufA   = (float*)(srcs + E);           // N*32
  float* bufB   = bufA + (size_t)N * NCH;       // N*32

  const int bn = 256;
  const int gN   = (N + bn - 1) / bn;
  const int gE   = (E + bn - 1) / bn;
  const int gN32 = (int)(((long long)N * NCH + bn - 1) / bn);
  const int NB   = (N + SCAN_CHUNK - 1) / SCAN_CHUNK;  // 25

  // CSR build (cursor doubles as the count array during histogram)
  k_zero<<<gN, bn, 0, stream>>>(cursor, N);
  k_cnt<<<gE, bn, 0, stream>>>(ei, cursor, E);
  k_dis<<<gN, bn, 0, stream>>>(cursor, dis, N);
  k_blockscan<<<NB, 256, 0, stream>>>(cursor, rowptr, bsum, N);
  k_scanb<<<1, 64, 0, stream>>>(bsum, NB);
  k_addoff<<<gN, bn, 0, stream>>>(rowptr, bsum, cursor, N, E);
  k_place<<<gE, bn, 0, stream>>>(ei, cursor, srcs, E);

  // layer 1: linear -> gather-aggregate (+b1, relu)
  k_gemm1<<<gN32, bn, 0, stream>>>(x, W1, dis, bufA, N);
  k_agg1<<<gN32, bn, 0, stream>>>(rowptr, srcs, bufA, dis, b1, bufB, N);

  // layer 2: linear -> gather-aggregate (+b2, relu) fused with classifier head
  k_gemm2<<<gN32, bn, 0, stream>>>(bufB, W2, dis, bufA, N);
  k_agg2_head<<<gN32, bn, 0, stream>>>(rowptr, srcs, bufA, dis, b2, Wc, bc, out, N);
}

// Round 3
// 317.748 us; speedup vs baseline: 2.9161x; 2.2597x over previous
//
#include <hip/hip_runtime.h>

#define NCH 32
#define INCH 128
#define SH 7                  // nodes per bucket = 128
#define BNODES 128
#define CAP 4544              // per-bucket capacity: avg 4092 + ~7 sigma
#define P1_CHUNK 8192
#define NBINS_PAD 1024        // padded bucket count for scan (needs N <= 131072)

// ---- init per-bucket write cursors ------------------------------------------
__global__ void k_initcur(int* gcur, int nbk) {
  int i = blockIdx.x * blockDim.x + threadIdx.x;
  if (i < nbk) gcur[i] = i * CAP;
}

// ---- P1: block-local counting sort into 782 coarse buckets, chunked copy-out -
__global__ __launch_bounds__(256) void k_part(const int* __restrict__ ei, int* gcur,
                                              unsigned int* __restrict__ srcsb, int E) {
  __shared__ unsigned int sorted[P1_CHUNK];
  __shared__ int hist[NBINS_PAD];       // counts, later reused to hold global dest
  __shared__ int bbase[NBINS_PAD + 1];  // exclusive scan (local run starts)
  __shared__ int bfill[NBINS_PAD];      // placement cursors
  __shared__ int wsums[4];
  const int tid = threadIdx.x;
  const int base = blockIdx.x * P1_CHUNK;
  const int cnt = min(P1_CHUNK, E - base);

  for (int i = tid; i < NBINS_PAD; i += 256) hist[i] = 0;
  __syncthreads();
  // pass 1: histogram by coarse bucket
  for (int i = tid; i < cnt; i += 256) {
    int d = ei[E + base + i];
    atomicAdd(&hist[d >> SH], 1);
  }
  __syncthreads();
  // exclusive scan of 1024 bins: 4 serial per thread + wave scan + wave offsets
  int c0 = hist[4 * tid], c1 = hist[4 * tid + 1], c2 = hist[4 * tid + 2], c3 = hist[4 * tid + 3];
  int s = c0 + c1 + c2 + c3;
  int lane = tid & 63, w = tid >> 6;
  int incl = s;
#pragma unroll
  for (int off = 1; off < 64; off <<= 1) {
    int t = __shfl_up(incl, off, 64);
    if (lane >= off) incl += t;
  }
  if (lane == 63) wsums[w] = incl;
  __syncthreads();
  int woff = 0;
  for (int i = 0; i < w; ++i) woff += wsums[i];
  int te = woff + incl - s;
  bbase[4 * tid] = te;            bfill[4 * tid] = te;
  bbase[4 * tid + 1] = te + c0;   bfill[4 * tid + 1] = te + c0;
  bbase[4 * tid + 2] = te + c0 + c1;       bfill[4 * tid + 2] = te + c0 + c1;
  bbase[4 * tid + 3] = te + c0 + c1 + c2;  bfill[4 * tid + 3] = te + c0 + c1 + c2;
  if (tid == 255) bbase[NBINS_PAD] = te + s;  // == cnt
  __syncthreads();
  // pass 2: place packed (dstlow<<17 | src) into block-sorted LDS
  for (int i = tid; i < cnt; i += 256) {
    int d = ei[E + base + i];
    int srcv = ei[base + i];
    int b = d >> SH;
    int pos = atomicAdd(&bfill[b], 1);
    sorted[pos] = ((unsigned int)(d & (BNODES - 1)) << 17) | (unsigned int)srcv;
  }
  __syncthreads();
  // reserve global space per bucket (one atomic per non-empty bucket)
  for (int b = tid; b < NBINS_PAD; b += 256) {
    int c = bbase[b + 1] - bbase[b];
    hist[b] = (c > 0) ? atomicAdd(&gcur[b], c) : 0;
  }
  __syncthreads();
  // copy-out: consecutive i -> contiguous runs; find bucket via binary search
  for (int i = tid; i < cnt; i += 256) {
    int lo = 0, hi = NBINS_PAD - 1;
#pragma unroll
    for (int it = 0; it < 10; ++it) {
      int mid = (lo + hi + 1) >> 1;
      if (bbase[mid] <= i) lo = mid; else hi = mid - 1;
    }
    int gpos = hist[lo] + (i - bbase[lo]);
    if (gpos < (lo + 1) * CAP) srcsb[gpos] = sorted[i];  // clamp vs overflow
  }
}

// ---- P2: per-bucket counting sort by node; emit rowbeg/rowend/dis ------------
__global__ __launch_bounds__(256) void k_bsort(const int* __restrict__ gcur,
                                               unsigned int* __restrict__ srcsb,
                                               int* __restrict__ rowbeg, int* __restrict__ rowend,
                                               float* __restrict__ dis, int N) {
  __shared__ unsigned int raw[CAP];
  __shared__ unsigned int sbuf[CAP];
  __shared__ int hist2[BNODES];
  __shared__ int sc[BNODES];
  __shared__ int fill2[BNODES];
  const int tid = threadIdx.x;
  const int bin = blockIdx.x;
  const int base = bin * CAP;
  int cnt = min(gcur[bin] - base, CAP);

  if (tid < BNODES) hist2[tid] = 0;
  for (int i = tid; i < cnt; i += 256) raw[i] = srcsb[base + i];
  __syncthreads();
  for (int i = tid; i < cnt; i += 256) atomicAdd(&hist2[raw[i] >> 17], 1);
  __syncthreads();
  int deg = (tid < BNODES) ? hist2[tid] : 0;
  if (tid < BNODES) sc[tid] = deg;
  __syncthreads();
  for (int off = 1; off < BNODES; off <<= 1) {
    int t = 0;
    if (tid < BNODES && tid >= off) t = sc[tid - off];
    __syncthreads();
    if (tid < BNODES) sc[tid] += t;
    __syncthreads();
  }
  int excl = 0;
  if (tid < BNODES) { excl = sc[tid] - deg; fill2[tid] = excl; }
  __syncthreads();
  for (int i = tid; i < cnt; i += 256) {
    unsigned int v = raw[i];
    int pos = atomicAdd(&fill2[v >> 17], 1);
    sbuf[pos] = v & 0x1FFFFu;
  }
  __syncthreads();
  for (int i = tid; i < cnt; i += 256) srcsb[base + i] = sbuf[i];  // coalesced
  if (tid < BNODES) {
    int n = bin * BNODES + tid;
    if (n < N) {
      rowbeg[n] = base + excl;
      rowend[n] = base + excl + deg;
      dis[n] = rsqrtf((float)(deg + 1));
    }
  }
}

// ---- layer 1 linear: hs[n][c] = (x[n]·W1[:,c]) * dis[n] ---------------------
__global__ __launch_bounds__(256) void k_gemm1(const float* __restrict__ x,
                                               const float* __restrict__ W1,
                                               const float* __restrict__ dis,
                                               float* __restrict__ hs, int N) {
  __shared__ float w[INCH * NCH];
  for (int i = threadIdx.x; i < INCH * NCH; i += blockDim.x) w[i] = W1[i];
  __syncthreads();
  int t = blockIdx.x * blockDim.x + threadIdx.x;
  int n = t >> 5, c = t & 31;
  if (n >= N) return;
  const float* xr = x + (size_t)n * INCH;
  float acc = 0.f;
#pragma unroll
  for (int k = 0; k < INCH; ++k) acc = fmaf(xr[k], w[k * NCH + c], acc);
  hs[(size_t)n * NCH + c] = acc * dis[n];
}

// ---- agg1 + layer-2 linear fused: hs2 = (relu(dis*(self+Σ)+b1) @ W2) * dis --
__global__ __launch_bounds__(256) void k_agg1g2(
    const int* __restrict__ rowbeg, const int* __restrict__ rowend,
    const unsigned int* __restrict__ srcs, const float* __restrict__ hs,
    const float* __restrict__ dis, const float* __restrict__ b1,
    const float* __restrict__ W2, float* __restrict__ hs2, int N) {
  __shared__ float w[NCH * NCH];
  for (int i = threadIdx.x; i < NCH * NCH; i += blockDim.x) w[i] = W2[i];
  __syncthreads();
  int t = blockIdx.x * blockDim.x + threadIdx.x;
  int n = t >> 5, c = t & 31;
  if (n >= N) return;
  int j = rowbeg[n], end = rowend[n];
  float acc = hs[(size_t)n * NCH + c];  // self loop
  for (; j + 4 <= end; j += 4) {
    unsigned int s0 = srcs[j], s1 = srcs[j + 1], s2 = srcs[j + 2], s3 = srcs[j + 3];
    float a0 = hs[(size_t)s0 * NCH + c];
    float a1 = hs[(size_t)s1 * NCH + c];
    float a2 = hs[(size_t)s2 * NCH + c];
    float a3 = hs[(size_t)s3 * NCH + c];
    acc += (a0 + a1) + (a2 + a3);
  }
  for (; j < end; ++j) acc += hs[(size_t)srcs[j] * NCH + c];
  float dn = dis[n];
  float v = fmaxf(fmaf(acc, dn, b1[c]), 0.f);
  float acc2 = 0.f;
#pragma unroll
  for (int k = 0; k < NCH; ++k) acc2 = fmaf(__shfl(v, k, 32), w[k * NCH + c], acc2);
  hs2[(size_t)n * NCH + c] = acc2 * dn;
}

// ---- agg2 + head: v=relu(dis*(self+Σ)+b2); out[n] = v·Wc + bc ---------------
__global__ __launch_bounds__(256) void k_agg2h(
    const int* __restrict__ rowbeg, const int* __restrict__ rowend,
    const unsigned int* __restrict__ srcs, const float* __restrict__ hs2,
    const float* __restrict__ dis, const float* __restrict__ b2,
    const float* __restrict__ Wc, const float* __restrict__ bc,
    float* __restrict__ out, int N) {
  int t = blockIdx.x * blockDim.x + threadIdx.x;
  int n = t >> 5, c = t & 31;
  if (n >= N) return;
  int j = rowbeg[n], end = rowend[n];
  float acc = hs2[(size_t)n * NCH + c];
  for (; j + 4 <= end; j += 4) {
    unsigned int s0 = srcs[j], s1 = srcs[j + 1], s2 = srcs[j + 2], s3 = srcs[j + 3];
    float a0 = hs2[(size_t)s0 * NCH + c];
    float a1 = hs2[(size_t)s1 * NCH + c];
    float a2 = hs2[(size_t)s2 * NCH + c];
    float a3 = hs2[(size_t)s3 * NCH + c];
    acc += (a0 + a1) + (a2 + a3);
  }
  for (; j < end; ++j) acc += hs2[(size_t)srcs[j] * NCH + c];
  float v = fmaxf(fmaf(acc, dis[n], b2[c]), 0.f);
  float s0 = v * Wc[c * 2 + 0];
  float s1 = v * Wc[c * 2 + 1];
#pragma unroll
  for (int off = 16; off > 0; off >>= 1) {
    s0 += __shfl_down(s0, off, 32);
    s1 += __shfl_down(s1, off, 32);
  }
  if (c == 0) {
    out[(size_t)n * 2 + 0] = s0 + bc[0];
    out[(size_t)n * 2 + 1] = s1 + bc[1];
  }
}

extern "C" void kernel_launch(void* const* d_in, const int* in_sizes, int n_in,
                              void* d_out, int out_size, void* d_ws, size_t ws_size,
                              hipStream_t stream) {
  const float* x  = (const float*)d_in[0];
  const int*   ei = (const int*)d_in[1];
  const float* W1 = (const float*)d_in[2];
  const float* b1 = (const float*)d_in[3];
  const float* W2 = (const float*)d_in[4];
  const float* b2 = (const float*)d_in[5];
  const float* Wc = (const float*)d_in[6];
  const float* bc = (const float*)d_in[7];
  float* out = (float*)d_out;

  const int N = in_sizes[0] / INCH;  // 100000
  const int E = in_sizes[1] / 2;     // 3200000
  const int nbk = (N + BNODES - 1) / BNODES;  // 782

  // workspace layout (4B elems)
  float*        dis    = (float*)d_ws;                  // N
  int*          rowbeg = (int*)(dis + N);               // N
  int*          rowend = rowbeg + N;                    // N
  int*          gcur   = rowend + N;                    // nbk
  unsigned int* srcsb  = (unsigned int*)(gcur + nbk);   // nbk*CAP
  float*        bufA   = (float*)(srcsb + (size_t)nbk * CAP);  // N*32
  float*        bufB   = bufA + (size_t)N * NCH;               // N*32

  const int bn = 256;
  const int gN32 = (int)(((long long)N * NCH + bn - 1) / bn);
  const int gP1  = (E + P1_CHUNK - 1) / P1_CHUNK;  // 391

  k_initcur<<<(nbk + bn - 1) / bn, bn, 0, stream>>>(gcur, nbk);
  k_part<<<gP1, bn, 0, stream>>>(ei, gcur, srcsb, E);
  k_bsort<<<nbk, bn, 0, stream>>>(gcur, srcsb, rowbeg, rowend, dis, N);

  k_gemm1<<<gN32, bn, 0, stream>>>(x, W1, dis, bufA, N);
  k_agg1g2<<<gN32, bn, 0, stream>>>(rowbeg, rowend, srcsb, bufA, dis, b1, W2, bufB, N);
  k_agg2h<<<gN32, bn, 0, stream>>>(rowbeg, rowend, srcsb, bufB, dis, b2, Wc, bc, out, N);
}